// Round 11
// baseline (339.887 us; speedup 1.0000x reference)
//
#include <hip/hip_runtime.h>
#include <hip/hip_bf16.h>
#include <math.h>

#define N_NODES 10000
#define N_EDGES 160000
#define N_GRAPHS 64
#define F_IN    128
#define C1_DIM  128
#define C2_DIM  256
#define C3_DIM  512
#define K_CHEB  5
#define NCLS    10
#define TC      (K_CHEB * F_IN)    // 640
#define LDSW1   136                // LDS row stride (shorts) for C=128 (272 B, 16B-aligned, 2-way banks)
#define LDSW2   264                // for C=256 (528 B)

typedef short v8s __attribute__((ext_vector_type(8)));
typedef float v4f __attribute__((ext_vector_type(4)));

// ---------- bf16 helpers ----------
static __device__ __forceinline__ unsigned short f2bf(float f) {
    unsigned u = __float_as_uint(f);
    unsigned r = (u + 0x7FFFu + ((u >> 16) & 1u)) >> 16;   // RNE
    return (unsigned short)r;
}
static __device__ __forceinline__ float bf_lo(unsigned u) { return __uint_as_float(u << 16); }
static __device__ __forceinline__ float bf_hi(unsigned u) { return __uint_as_float(u & 0xFFFF0000u); }

// ---------- fused prep ----------
#define PREP_A (N_NODES * 32)            // x conv, 4 floats per item
#define PREP_B (TC * C1_DIM)             // W_cheb transpose (write-coalesced)
#define PREP_C (C1_DIM * C2_DIM)         // W_g1
#define PREP_D (C2_DIM * C3_DIM)         // W_g2
#define PREP_E N_NODES                   // gptr
#define PREP_F N_NODES                   // zero logits
#define PREP_G N_EDGES                   // degree count
#define PREP_TOTAL (PREP_A + PREP_B + PREP_C + PREP_D + PREP_E + PREP_F + PREP_G)
__global__ void prep_kernel(const float* __restrict__ x, unsigned short* __restrict__ tcat,
                            const float* __restrict__ Wcheb, unsigned short* __restrict__ Wcb_t,
                            const float* __restrict__ Wg1, unsigned short* __restrict__ Wg1_t,
                            const float* __restrict__ Wg2, unsigned short* __restrict__ Wg2_t,
                            const int* __restrict__ batch, int* __restrict__ gptr,
                            float* __restrict__ logits,
                            const int* __restrict__ src, const int* __restrict__ dst,
                            int* __restrict__ cnt_s, int* __restrict__ cnt_d) {
    int id = blockIdx.x * blockDim.x + threadIdx.x;
    if (id < PREP_A) {
        int n = id >> 5, f = (id & 31) * 4;
        float4 v = *(const float4*)(x + (size_t)n * F_IN + f);
        ushort4 o; o.x = f2bf(v.x); o.y = f2bf(v.y); o.z = f2bf(v.z); o.w = f2bf(v.w);
        *(ushort4*)(tcat + (size_t)n * TC + f) = o;
        return;
    }
    id -= PREP_A;
    if (id < PREP_B) {
        int k = id % TC, n = id / TC;
        Wcb_t[(size_t)n * TC + k] = f2bf(Wcheb[(size_t)k * C1_DIM + n]);
        return;
    }
    id -= PREP_B;
    if (id < PREP_C) {
        int k = id % C1_DIM, n = id / C1_DIM;
        Wg1_t[(size_t)n * C1_DIM + k] = f2bf(Wg1[(size_t)k * C2_DIM + n]);
        return;
    }
    id -= PREP_C;
    if (id < PREP_D) {
        int k = id % C2_DIM, n = id / C2_DIM;
        Wg2_t[(size_t)n * C2_DIM + k] = f2bf(Wg2[(size_t)k * C3_DIM + n]);
        return;
    }
    id -= PREP_D;
    if (id < PREP_E) {
        int i = id;
        int b = batch[i];
        if (i == 0) { for (int g = 0; g <= b; g++) gptr[g] = 0; }
        else {
            int bp = batch[i - 1];
            for (int g = bp + 1; g <= b; g++) gptr[g] = i;
        }
        if (i == N_NODES - 1) { for (int g = b + 1; g <= N_GRAPHS; g++) gptr[g] = N_NODES; }
        return;
    }
    id -= PREP_E;
    if (id < PREP_F) { logits[id] = 0.0f; return; }
    id -= PREP_F;
    if (id < PREP_G) {   // guarded tail (R6 lesson)
        atomicAdd(&cnt_s[src[id]], 1);
        atomicAdd(&cnt_d[dst[id]], 1);
    }
}

// ---------- CSR: scan (LDS-staged, coalesced) ----------
__global__ __launch_bounds__(256) void scan_kernel(const int* __restrict__ cnt_d,
                                                   int* __restrict__ rowptr, int n) {
    __shared__ int ldsc[N_NODES];
    __shared__ int sums[256];
    int tid = threadIdx.x;
    for (int i = tid; i < n; i += 256) ldsc[i] = cnt_d[i];
    __syncthreads();
    int chunk = (n + 255) / 256;
    int s0 = min(n, tid * chunk), s1 = min(n, s0 + chunk);
    int loc = 0;
    for (int i = s0; i < s1; i++) loc += ldsc[i];
    sums[tid] = loc;
    __syncthreads();
    for (int off = 1; off < 256; off <<= 1) {
        int t = (tid >= off) ? sums[tid - off] : 0;
        __syncthreads();
        sums[tid] += t;
        __syncthreads();
    }
    int pre = sums[tid] - loc;
    for (int i = s0; i < s1; i++) { int v = ldsc[i]; ldsc[i] = pre; pre += v; }
    __syncthreads();
    for (int i = tid; i < n; i += 256) rowptr[i] = ldsc[i];
    if (tid == 255) rowptr[n] = pre;
}

// ---------- CSR: fill -> packed (col, weight) records ----------
__global__ void fill_kernel(const int* __restrict__ src, const int* __restrict__ dst,
                            const int* __restrict__ cnt_s, const int* __restrict__ cnt_d,
                            const int* __restrict__ rowptr, int* __restrict__ fillc,
                            int2* __restrict__ ecb, int2* __restrict__ egc, int E) {
    int e = blockIdx.x * blockDim.x + threadIdx.x;
    if (e >= E) return;
    int s = src[e], d = dst[e];
    int pos = rowptr[d] + atomicAdd(&fillc[d], 1);
    int cs = cnt_s[s], cd = cnt_s[d];
    float ds = (cs > 0) ? rsqrtf((float)cs) : 0.0f;
    float dd = (cd > 0) ? rsqrtf((float)cd) : 0.0f;
    float nr = rsqrtf((float)cnt_d[s] + 1.0f) * rsqrtf((float)cnt_d[d] + 1.0f);
    ecb[pos] = make_int2(s, __float_as_int(-(ds * dd)));
    egc[pos] = make_int2(s, __float_as_int(nr));
}

// ---------- standalone Cheb gather (T1..T3), 16x edge-unrolled ----------
__global__ __launch_bounds__(256) void gather_cheb_bf(
        const unsigned short* __restrict__ tb, const int* __restrict__ rowptr,
        const int2* __restrict__ edges,
        const unsigned short* __restrict__ base, float alpha, float beta,
        unsigned short* __restrict__ outc, int n) {
    int w = (blockIdx.x * blockDim.x + threadIdx.x) >> 6;
    int lane = threadIdx.x & 63;
    if (w >= n) return;
    float a0 = 0.0f, a1 = 0.0f;
    int rs = rowptr[w], re = rowptr[w + 1];
    for (int b = rs; b < re; b += 64) {
        int cl = 0; float wl = 0.0f;
        if (b + lane < re) { int2 e = edges[b + lane]; cl = e.x; wl = __int_as_float(e.y); }
        int nk16 = (min(64, re - b) + 15) & ~15;
        for (int j = 0; j < nk16; j += 16) {
            int ss[16]; float ww[16]; unsigned uu[16];
            #pragma unroll
            for (int q = 0; q < 16; q++) { ss[q] = __shfl(cl, j + q); ww[q] = __shfl(wl, j + q); }
            #pragma unroll
            for (int q = 0; q < 16; q++) uu[q] = ((const unsigned*)(tb + (size_t)ss[q] * TC))[lane];
            #pragma unroll
            for (int q = 0; q < 16; q++) { a0 += ww[q] * bf_lo(uu[q]); a1 += ww[q] * bf_hi(uu[q]); }
        }
    }
    if (base) {
        unsigned ub = ((const unsigned*)(base + (size_t)w * TC))[lane];
        a0 = alpha * a0 + beta * bf_lo(ub);
        a1 = alpha * a1 + beta * bf_hi(ub);
    } else {
        a0 *= alpha; a1 *= alpha;
    }
    ushort2 o; o.x = f2bf(a0); o.y = f2bf(a1);
    *(ushort2*)(outc + (size_t)w * TC + lane * 2) = o;
}

// ---------- FUSED: T4 gather -> LDS, then GEMM1 (64x128 tile, K=640) ----------
__global__ __launch_bounds__(256) void cheb4_gemm1(
        const unsigned short* __restrict__ tcat, const int* __restrict__ rowptr,
        const int2* __restrict__ ecb, const unsigned short* __restrict__ Bt,
        const float* __restrict__ bias, unsigned short* __restrict__ h1b, int M) {
    __shared__ unsigned short ldsA[64 * LDSW1];   // T4 rows, 17 KB
    int tid = threadIdx.x, wave = tid >> 6, lane = tid & 63;
    int m0 = blockIdx.x * 64;
    const unsigned short* t3 = tcat + 3 * F_IN;
    const unsigned short* t2 = tcat + 2 * F_IN;

    // gather: T4 = 2*prop(T3) - T2 for 16 nodes per wave
    for (int na = wave * 16; na < wave * 16 + 16; na++) {
        int w = m0 + na;
        float a0 = 0.0f, a1 = 0.0f;
        if (w < M) {
            int rs = rowptr[w], re = rowptr[w + 1];
            for (int b = rs; b < re; b += 64) {
                int cl = 0; float wl = 0.0f;
                if (b + lane < re) { int2 e = ecb[b + lane]; cl = e.x; wl = __int_as_float(e.y); }
                int nk16 = (min(64, re - b) + 15) & ~15;
                for (int j = 0; j < nk16; j += 16) {
                    int ss[16]; float ww[16]; unsigned uu[16];
                    #pragma unroll
                    for (int q = 0; q < 16; q++) { ss[q] = __shfl(cl, j + q); ww[q] = __shfl(wl, j + q); }
                    #pragma unroll
                    for (int q = 0; q < 16; q++) uu[q] = ((const unsigned*)(t3 + (size_t)ss[q] * TC))[lane];
                    #pragma unroll
                    for (int q = 0; q < 16; q++) { a0 += ww[q] * bf_lo(uu[q]); a1 += ww[q] * bf_hi(uu[q]); }
                }
            }
            unsigned ub = ((const unsigned*)(t2 + (size_t)w * TC))[lane];
            a0 = 2.0f * a0 - bf_lo(ub);
            a1 = 2.0f * a1 - bf_hi(ub);
        }
        ushort2 o; o.x = f2bf(a0); o.y = f2bf(a1);
        *(ushort2*)(ldsA + na * LDSW1 + lane * 2) = o;
    }
    __syncthreads();

    // GEMM: waves 2x2, wave tile 32x64 (i=2, JT=4), K=640 (k<512 global, k>=512 LDS)
    int wm = (wave & 1) * 32, wn = (wave >> 1) * 64;
    int l15 = lane & 15, quad = lane >> 4;
    v4f acc[2][4];
    #pragma unroll
    for (int i = 0; i < 2; i++)
        #pragma unroll
        for (int j = 0; j < 4; j++) acc[i][j] = (v4f){0.f, 0.f, 0.f, 0.f};
    const unsigned short* Ab[2]; bool av[2]; int rl[2];
    #pragma unroll
    for (int i = 0; i < 2; i++) {
        int row = m0 + wm + i * 16 + l15;
        av[i] = row < M;
        Ab[i] = tcat + (size_t)(av[i] ? row : 0) * TC + quad * 8;
        rl[i] = wm + i * 16 + l15;
    }
    const unsigned short* Bb[4];
    #pragma unroll
    for (int j = 0; j < 4; j++) {
        int coln = wn + j * 16 + l15;
        Bb[j] = Bt + (size_t)coln * TC + quad * 8;
    }
    const v8s zero8 = {0, 0, 0, 0, 0, 0, 0, 0};
    #pragma unroll
    for (int k0 = 0; k0 < TC; k0 += 32) {
        v8s a[2], b[4];
        #pragma unroll
        for (int i = 0; i < 2; i++) {
            if (k0 < 4 * F_IN) a[i] = av[i] ? *(const v8s*)(Ab[i] + k0) : zero8;
            else               a[i] = *(const v8s*)(ldsA + rl[i] * LDSW1 + (k0 - 4 * F_IN) + quad * 8);
        }
        #pragma unroll
        for (int j = 0; j < 4; j++) b[j] = *(const v8s*)(Bb[j] + k0);
        #pragma unroll
        for (int i = 0; i < 2; i++)
            #pragma unroll
            for (int j = 0; j < 4; j++)
                acc[i][j] = __builtin_amdgcn_mfma_f32_16x16x32_bf16(a[i], b[j], acc[i][j], 0, 0, 0);
    }
    #pragma unroll
    for (int j = 0; j < 4; j++) {
        int coln = wn + j * 16 + l15;
        float bv = bias[coln];
        #pragma unroll
        for (int i = 0; i < 2; i++) {
            #pragma unroll
            for (int r = 0; r < 4; r++) {
                int row = m0 + wm + i * 16 + quad * 4 + r;
                if (row >= M) continue;
                float v = fmaxf(acc[i][j][r] + bv, 0.0f);
                h1b[(size_t)row * C1_DIM + coln] = f2bf(v);
            }
        }
    }
}

// ---------- FUSED: z1 gather -> LDS, GEMM2 (64x256 tile, K=128, A entirely LDS) ----------
__global__ __launch_bounds__(256) void gcn_gemm2(
        const unsigned short* __restrict__ h1b, const int* __restrict__ rowptr,
        const int2* __restrict__ egc, const int* __restrict__ cnt_d,
        const unsigned short* __restrict__ Bt, const float* __restrict__ bias,
        unsigned short* __restrict__ h2b, int M) {
    __shared__ unsigned short ldsA[64 * LDSW1];
    int tid = threadIdx.x, wave = tid >> 6, lane = tid & 63;
    int m0 = blockIdx.x * 64;

    for (int na = wave * 16; na < wave * 16 + 16; na++) {
        int w = m0 + na;
        float a0 = 0.0f, a1 = 0.0f;
        if (w < M) {
            int rs = rowptr[w], re = rowptr[w + 1];
            for (int b = rs; b < re; b += 64) {
                int cl = 0; float wl = 0.0f;
                if (b + lane < re) { int2 e = egc[b + lane]; cl = e.x; wl = __int_as_float(e.y); }
                int nk16 = (min(64, re - b) + 15) & ~15;
                for (int j = 0; j < nk16; j += 16) {
                    int ss[16]; float ww[16]; unsigned uu[16];
                    #pragma unroll
                    for (int q = 0; q < 16; q++) { ss[q] = __shfl(cl, j + q); ww[q] = __shfl(wl, j + q); }
                    #pragma unroll
                    for (int q = 0; q < 16; q++) uu[q] = ((const unsigned*)(h1b + (size_t)ss[q] * C1_DIM))[lane];
                    #pragma unroll
                    for (int q = 0; q < 16; q++) { a0 += ww[q] * bf_lo(uu[q]); a1 += ww[q] * bf_hi(uu[q]); }
                }
            }
            float sn = 1.0f / (float)(cnt_d[w] + 1);
            unsigned u = ((const unsigned*)(h1b + (size_t)w * C1_DIM))[lane];
            a0 += sn * bf_lo(u);
            a1 += sn * bf_hi(u);
        }
        ushort2 o; o.x = f2bf(a0); o.y = f2bf(a1);
        *(ushort2*)(ldsA + na * LDSW1 + lane * 2) = o;
    }
    __syncthreads();

    // GEMM: waves 2x2, wave tile 32x128 (i=2, JT=8), K=128 from LDS
    int wm = (wave & 1) * 32, wn = (wave >> 1) * 128;
    int l15 = lane & 15, quad = lane >> 4;
    v4f acc[2][8];
    #pragma unroll
    for (int i = 0; i < 2; i++)
        #pragma unroll
        for (int j = 0; j < 8; j++) acc[i][j] = (v4f){0.f, 0.f, 0.f, 0.f};
    int rl[2] = {wm + l15, wm + 16 + l15};
    const unsigned short* Bb[8];
    #pragma unroll
    for (int j = 0; j < 8; j++) {
        int coln = wn + j * 16 + l15;
        Bb[j] = Bt + (size_t)coln * C1_DIM + quad * 8;
    }
    #pragma unroll
    for (int k0 = 0; k0 < C1_DIM; k0 += 32) {
        v8s a[2], b[8];
        #pragma unroll
        for (int i = 0; i < 2; i++) a[i] = *(const v8s*)(ldsA + rl[i] * LDSW1 + k0 + quad * 8);
        #pragma unroll
        for (int j = 0; j < 8; j++) b[j] = *(const v8s*)(Bb[j] + k0);
        #pragma unroll
        for (int i = 0; i < 2; i++)
            #pragma unroll
            for (int j = 0; j < 8; j++)
                acc[i][j] = __builtin_amdgcn_mfma_f32_16x16x32_bf16(a[i], b[j], acc[i][j], 0, 0, 0);
    }
    #pragma unroll
    for (int j = 0; j < 8; j++) {
        int coln = wn + j * 16 + l15;
        float bv = bias[coln];
        #pragma unroll
        for (int i = 0; i < 2; i++) {
            #pragma unroll
            for (int r = 0; r < 4; r++) {
                int row = m0 + wm + i * 16 + quad * 4 + r;
                if (row >= M) continue;
                float v = fmaxf(acc[i][j][r] + bv, 0.0f);
                h2b[(size_t)row * C2_DIM + coln] = f2bf(v);
            }
        }
    }
}

// ---------- FUSED: z2 gather -> LDS, GEMM3 (64x512 tile, K=256) + gate dot ----------
__global__ __launch_bounds__(512) void gcn_gemm3(
        const unsigned short* __restrict__ h2b, const int* __restrict__ rowptr,
        const int2* __restrict__ egc, const int* __restrict__ cnt_d,
        const unsigned short* __restrict__ Bt, const float* __restrict__ bias,
        const float* __restrict__ wg, unsigned short* __restrict__ h3b,
        float* __restrict__ logits, int M) {
    __shared__ unsigned short ldsA[64 * LDSW2];   // 33 KB
    int tid = threadIdx.x, wave = tid >> 6, lane = tid & 63;   // 8 waves
    int m0 = blockIdx.x * 64;

    for (int na = wave * 8; na < wave * 8 + 8; na++) {
        int w = m0 + na;
        float a0 = 0.0f, a1 = 0.0f, a2 = 0.0f, a3 = 0.0f;
        if (w < M) {
            int rs = rowptr[w], re = rowptr[w + 1];
            for (int b = rs; b < re; b += 64) {
                int cl = 0; float wl = 0.0f;
                if (b + lane < re) { int2 e = egc[b + lane]; cl = e.x; wl = __int_as_float(e.y); }
                int nk16 = (min(64, re - b) + 15) & ~15;
                for (int j = 0; j < nk16; j += 16) {
                    int ss[16]; float ww[16]; uint2 uu[16];
                    #pragma unroll
                    for (int q = 0; q < 16; q++) { ss[q] = __shfl(cl, j + q); ww[q] = __shfl(wl, j + q); }
                    #pragma unroll
                    for (int q = 0; q < 16; q++) uu[q] = ((const uint2*)(h2b + (size_t)ss[q] * C2_DIM))[lane];
                    #pragma unroll
                    for (int q = 0; q < 16; q++) {
                        a0 += ww[q] * bf_lo(uu[q].x); a1 += ww[q] * bf_hi(uu[q].x);
                        a2 += ww[q] * bf_lo(uu[q].y); a3 += ww[q] * bf_hi(uu[q].y);
                    }
                }
            }
            float sn = 1.0f / (float)(cnt_d[w] + 1);
            uint2 u = ((const uint2*)(h2b + (size_t)w * C2_DIM))[lane];
            a0 += sn * bf_lo(u.x); a1 += sn * bf_hi(u.x);
            a2 += sn * bf_lo(u.y); a3 += sn * bf_hi(u.y);
        }
        ushort4 o; o.x = f2bf(a0); o.y = f2bf(a1); o.z = f2bf(a2); o.w = f2bf(a3);
        *(ushort4*)(ldsA + na * LDSW2 + lane * 4) = o;
    }
    __syncthreads();

    // GEMM: waves 2x4, wave tile 32x128 (i=2, JT=8), K=256 from LDS
    int wm = (wave >> 2) * 32, wn = (wave & 3) * 128;
    int l15 = lane & 15, quad = lane >> 4;
    v4f acc[2][8];
    #pragma unroll
    for (int i = 0; i < 2; i++)
        #pragma unroll
        for (int j = 0; j < 8; j++) acc[i][j] = (v4f){0.f, 0.f, 0.f, 0.f};
    int rl[2] = {wm + l15, wm + 16 + l15};
    const unsigned short* Bb[8];
    #pragma unroll
    for (int j = 0; j < 8; j++) {
        int coln = wn + j * 16 + l15;
        Bb[j] = Bt + (size_t)coln * C2_DIM + quad * 8;
    }
    #pragma unroll
    for (int k0 = 0; k0 < C2_DIM; k0 += 32) {
        v8s a[2], b[8];
        #pragma unroll
        for (int i = 0; i < 2; i++) a[i] = *(const v8s*)(ldsA + rl[i] * LDSW2 + k0 + quad * 8);
        #pragma unroll
        for (int j = 0; j < 8; j++) b[j] = *(const v8s*)(Bb[j] + k0);
        #pragma unroll
        for (int i = 0; i < 2; i++)
            #pragma unroll
            for (int j = 0; j < 8; j++)
                acc[i][j] = __builtin_amdgcn_mfma_f32_16x16x32_bf16(a[i], b[j], acc[i][j], 0, 0, 0);
    }
    float bv[8], wgj[8];
    #pragma unroll
    for (int j = 0; j < 8; j++) {
        int coln = wn + j * 16 + l15;
        bv[j] = bias[coln];
        wgj[j] = wg[coln];
    }
    #pragma unroll
    for (int i = 0; i < 2; i++) {
        #pragma unroll
        for (int r = 0; r < 4; r++) {
            int row = m0 + wm + i * 16 + quad * 4 + r;
            if (row >= M) continue;
            float gval = 0.0f;
            #pragma unroll
            for (int j = 0; j < 8; j++) {
                int coln = wn + j * 16 + l15;
                float v = fmaxf(acc[i][j][r] + bv[j], 0.0f);
                h3b[(size_t)row * C3_DIM + coln] = f2bf(v);
                gval += v * wgj[j];
            }
            #pragma unroll
            for (int off = 1; off < 16; off <<= 1) gval += __shfl_xor(gval, off);
            if (l15 == 0) atomicAdd(&logits[row], gval);
        }
    }
}

// ---------- FUSED pool + FC + log_softmax (pooled in LDS) ----------
__global__ __launch_bounds__(256) void pool_fc(const unsigned short* __restrict__ h3b,
        const float* __restrict__ logits, const int* __restrict__ gptr,
        const float* __restrict__ Wfc, const float* __restrict__ bfc,
        float* __restrict__ out) {
    __shared__ float red[256];
    __shared__ float plds[C3_DIM];
    int g = blockIdx.x, tid = threadIdx.x;
    int gs = gptr[g], ge = gptr[g + 1];
    float m = -INFINITY;
    for (int i = gs + tid; i < ge; i += 256) m = fmaxf(m, logits[i]);
    red[tid] = m; __syncthreads();
    for (int off = 128; off > 0; off >>= 1) {
        if (tid < off) red[tid] = fmaxf(red[tid], red[tid + off]);
        __syncthreads();
    }
    m = red[0]; __syncthreads();
    float s = 0.0f;
    for (int i = gs + tid; i < ge; i += 256) s += expf(logits[i] - m);
    red[tid] = s; __syncthreads();
    for (int off = 128; off > 0; off >>= 1) {
        if (tid < off) red[tid] += red[tid + off];
        __syncthreads();
    }
    s = red[0];
    float sinv = (s > 0.0f) ? 1.0f / s : 0.0f;
    float a0 = 0.0f, a1 = 0.0f;
    for (int i = gs; i < ge; i++) {
        float al = expf(logits[i] - m) * sinv;
        unsigned u = ((const unsigned*)(h3b + (size_t)i * C3_DIM))[tid];
        a0 += al * bf_lo(u);
        a1 += al * bf_hi(u);
    }
    plds[tid * 2 + 0] = a0;
    plds[tid * 2 + 1] = a1;
    __syncthreads();
    if (tid < 16) {
        float acc = -INFINITY;
        if (tid < NCLS) {
            acc = bfc[tid];
            for (int k = 0; k < C3_DIM; k++)
                acc += plds[k] * Wfc[k * NCLS + tid];
        }
        float mm = acc;
        #pragma unroll
        for (int off = 8; off > 0; off >>= 1) mm = fmaxf(mm, __shfl_xor(mm, off, 16));
        float e = (tid < NCLS) ? expf(acc - mm) : 0.0f;
        float ss = e;
        #pragma unroll
        for (int off = 8; off > 0; off >>= 1) ss += __shfl_xor(ss, off, 16);
        if (tid < NCLS) out[g * NCLS + tid] = acc - mm - logf(ss);
    }
}

// ---------- host ----------
extern "C" void kernel_launch(void* const* d_in, const int* in_sizes, int n_in,
                              void* d_out, int out_size, void* d_ws, size_t ws_size,
                              hipStream_t stream) {
    const float* x      = (const float*)d_in[0];
    const int*   ei     = (const int*)d_in[1];
    const int*   batch  = (const int*)d_in[2];
    const float* W_cheb = (const float*)d_in[3];
    const float* b_cheb = (const float*)d_in[4];
    const float* W_g1   = (const float*)d_in[5];
    const float* b_g1   = (const float*)d_in[6];
    const float* W_g2   = (const float*)d_in[7];
    const float* b_g2   = (const float*)d_in[8];
    const float* w_gate = (const float*)d_in[9];
    const float* W_fc   = (const float*)d_in[11];
    const float* b_fc   = (const float*)d_in[12];
    const int* src = ei;
    const int* dst = ei + N_EDGES;
    float* out = (float*)d_out;

    const int N = N_NODES, E = N_EDGES, G = N_GRAPHS;

    char* Wp = (char*)d_ws;
    auto alloc = [&](size_t bytes) {
        void* p = Wp;
        Wp += (bytes + 255) & ~(size_t)255;
        return p;
    };
    int*   cnt3    = (int*)alloc((size_t)3 * N * 4);
    int*   cnt_s   = cnt3;
    int*   cnt_d   = cnt3 + N;
    int*   fillc   = cnt3 + 2 * N;
    int*   rowptr  = (int*)alloc((N + 1) * 4);
    int2*  ecb     = (int2*)alloc((size_t)E * 8);
    int2*  egc     = (int2*)alloc((size_t)E * 8);
    unsigned short* tcat  = (unsigned short*)alloc((size_t)N * TC * 2);
    unsigned short* h1b   = (unsigned short*)alloc((size_t)N * C1_DIM * 2);
    unsigned short* h2b   = (unsigned short*)alloc((size_t)N * C2_DIM * 2);
    unsigned short* h3b   = (unsigned short*)alloc((size_t)N * C3_DIM * 2);
    unsigned short* Wcb_t = (unsigned short*)alloc((size_t)TC * C1_DIM * 2);
    unsigned short* Wg1_t = (unsigned short*)alloc((size_t)C1_DIM * C2_DIM * 2);
    unsigned short* Wg2_t = (unsigned short*)alloc((size_t)C2_DIM * C3_DIM * 2);
    float* logits  = (float*)alloc(N * 4);
    int*   gptr    = (int*)alloc((G + 1) * 4);

    dim3 blk(256);
    auto cdiv = [](int a, int b) { return (a + b - 1) / b; };

    // --- memset counters, fused prep ---
    hipMemsetAsync(cnt3, 0, (size_t)3 * N * sizeof(int), stream);
    hipLaunchKernelGGL(prep_kernel, dim3(cdiv(PREP_TOTAL, 256)), blk, 0, stream,
                       x, tcat, W_cheb, Wcb_t, W_g1, Wg1_t, W_g2, Wg2_t,
                       batch, gptr, logits, src, dst, cnt_s, cnt_d);

    // --- CSR scan + fill ---
    hipLaunchKernelGGL(scan_kernel, dim3(1), blk, 0, stream, cnt_d, rowptr, N);
    hipLaunchKernelGGL(fill_kernel, dim3(cdiv(E, 256)), blk, 0, stream,
                       src, dst, cnt_s, cnt_d, rowptr, fillc, ecb, egc, E);

    const int NWB = cdiv(N, 4);

    // --- Cheb T1..T3 (standalone gathers) ---
    hipLaunchKernelGGL(gather_cheb_bf, dim3(NWB), blk, 0, stream,
                       tcat + 0 * F_IN, rowptr, ecb,
                       (const unsigned short*)nullptr, 1.0f, 0.0f, tcat + 1 * F_IN, N);
    hipLaunchKernelGGL(gather_cheb_bf, dim3(NWB), blk, 0, stream,
                       tcat + 1 * F_IN, rowptr, ecb,
                       tcat + 0 * F_IN, 2.0f, -1.0f, tcat + 2 * F_IN, N);
    hipLaunchKernelGGL(gather_cheb_bf, dim3(NWB), blk, 0, stream,
                       tcat + 2 * F_IN, rowptr, ecb,
                       tcat + 1 * F_IN, 2.0f, -1.0f, tcat + 3 * F_IN, N);

    // --- fused T4-gather + GEMM1 ---
    hipLaunchKernelGGL(cheb4_gemm1, dim3(cdiv(N, 64)), blk, 0, stream,
                       tcat, rowptr, ecb, Wcb_t, b_cheb, h1b, N);

    // --- fused z1-gather + GEMM2 ---
    hipLaunchKernelGGL(gcn_gemm2, dim3(cdiv(N, 64)), blk, 0, stream,
                       h1b, rowptr, egc, cnt_d, Wg1_t, b_g1, h2b, N);

    // --- fused z2-gather + GEMM3 + gate ---
    hipLaunchKernelGGL(gcn_gemm3, dim3(cdiv(N, 64)), dim3(512), 0, stream,
                       h2b, rowptr, egc, cnt_d, Wg2_t, b_g2, w_gate, h3b, logits, N);

    // --- fused pool + FC ---
    hipLaunchKernelGGL(pool_fc, dim3(G), blk, 0, stream,
                       h3b, logits, gptr, W_fc, b_fc, out);
}

// Round 12
// 290.891 us; speedup vs baseline: 1.1684x; 1.1684x over previous
//
#include <hip/hip_runtime.h>
#include <hip/hip_bf16.h>
#include <math.h>

#define N_NODES 10000
#define N_EDGES 160000
#define N_GRAPHS 64
#define F_IN    128
#define C1_DIM  128
#define C2_DIM  256
#define C3_DIM  512
#define K_CHEB  5
#define NCLS    10
#define TC      (K_CHEB * F_IN)    // 640

typedef short v8s __attribute__((ext_vector_type(8)));
typedef float v4f __attribute__((ext_vector_type(4)));

// ---------- bf16 helpers ----------
static __device__ __forceinline__ unsigned short f2bf(float f) {
    unsigned u = __float_as_uint(f);
    unsigned r = (u + 0x7FFFu + ((u >> 16) & 1u)) >> 16;   // RNE
    return (unsigned short)r;
}
static __device__ __forceinline__ float bf_lo(unsigned u) { return __uint_as_float(u << 16); }
static __device__ __forceinline__ float bf_hi(unsigned u) { return __uint_as_float(u & 0xFFFF0000u); }

// ---------- fused prep ----------
#define PREP_A (N_NODES * 32)            // x conv, 4 floats per item
#define PREP_B (TC * C1_DIM)             // W_cheb transpose (write-coalesced)
#define PREP_C (C1_DIM * C2_DIM)         // W_g1
#define PREP_D (C2_DIM * C3_DIM)         // W_g2
#define PREP_E N_NODES                   // gptr
#define PREP_F N_NODES                   // zero logits
#define PREP_H (N_GRAPHS * C3_DIM)       // zero pooled
#define PREP_I N_GRAPHS                  // zero gdone
#define PREP_G N_EDGES                   // degree count (guarded tail)
#define PREP_TOTAL (PREP_A + PREP_B + PREP_C + PREP_D + PREP_E + PREP_F + PREP_H + PREP_I + PREP_G)
__global__ void prep_kernel(const float* __restrict__ x, unsigned short* __restrict__ tcat,
                            const float* __restrict__ Wcheb, unsigned short* __restrict__ Wcb_t,
                            const float* __restrict__ Wg1, unsigned short* __restrict__ Wg1_t,
                            const float* __restrict__ Wg2, unsigned short* __restrict__ Wg2_t,
                            const int* __restrict__ batch, int* __restrict__ gptr,
                            float* __restrict__ logits, float* __restrict__ pooled,
                            int* __restrict__ gdone,
                            const int* __restrict__ src, const int* __restrict__ dst,
                            int* __restrict__ cnt_s, int* __restrict__ cnt_d) {
    int id = blockIdx.x * blockDim.x + threadIdx.x;
    if (id < PREP_A) {
        int n = id >> 5, f = (id & 31) * 4;
        float4 v = *(const float4*)(x + (size_t)n * F_IN + f);
        ushort4 o; o.x = f2bf(v.x); o.y = f2bf(v.y); o.z = f2bf(v.z); o.w = f2bf(v.w);
        *(ushort4*)(tcat + (size_t)n * TC + f) = o;
        return;
    }
    id -= PREP_A;
    if (id < PREP_B) {
        int k = id % TC, n = id / TC;
        Wcb_t[(size_t)n * TC + k] = f2bf(Wcheb[(size_t)k * C1_DIM + n]);
        return;
    }
    id -= PREP_B;
    if (id < PREP_C) {
        int k = id % C1_DIM, n = id / C1_DIM;
        Wg1_t[(size_t)n * C1_DIM + k] = f2bf(Wg1[(size_t)k * C2_DIM + n]);
        return;
    }
    id -= PREP_C;
    if (id < PREP_D) {
        int k = id % C2_DIM, n = id / C2_DIM;
        Wg2_t[(size_t)n * C2_DIM + k] = f2bf(Wg2[(size_t)k * C3_DIM + n]);
        return;
    }
    id -= PREP_D;
    if (id < PREP_E) {
        int i = id;
        int b = batch[i];
        if (i == 0) { for (int g = 0; g <= b; g++) gptr[g] = 0; }
        else {
            int bp = batch[i - 1];
            for (int g = bp + 1; g <= b; g++) gptr[g] = i;
        }
        if (i == N_NODES - 1) { for (int g = b + 1; g <= N_GRAPHS; g++) gptr[g] = N_NODES; }
        return;
    }
    id -= PREP_E;
    if (id < PREP_F) { logits[id] = 0.0f; return; }
    id -= PREP_F;
    if (id < PREP_H) { pooled[id] = 0.0f; return; }
    id -= PREP_H;
    if (id < PREP_I) { gdone[id] = 0; return; }
    id -= PREP_I;
    if (id < PREP_G) {   // guarded tail (R6 lesson)
        atomicAdd(&cnt_s[src[id]], 1);
        atomicAdd(&cnt_d[dst[id]], 1);
    }
}

// ---------- CSR fill with EMBEDDED per-block redundant scan (no scan stage) ----------
// Every block computes the same exclusive scan of cnt_d in LDS (broadcast-friendly
// L2 reads, ~2 us, no cross-block dependency -> deadlock-free), then fills its
// 256 edges using the LDS prefix. Block 0 also writes global rowptr for gathers.
__global__ __launch_bounds__(256) void fill_scan_kernel(
        const int* __restrict__ src, const int* __restrict__ dst,
        const int* __restrict__ cnt_s, const int* __restrict__ cnt_d,
        int* __restrict__ rowptr, int* __restrict__ fillc,
        int2* __restrict__ ecb, int2* __restrict__ egc, int E, int n) {
    __shared__ int ldsc[N_NODES];
    __shared__ int sums[256];
    int tid = threadIdx.x;
    for (int i = tid; i < n; i += 256) ldsc[i] = cnt_d[i];
    __syncthreads();
    int chunk = (n + 255) / 256;
    int s0 = min(n, tid * chunk), s1 = min(n, s0 + chunk);
    int loc = 0;
    for (int i = s0; i < s1; i++) loc += ldsc[i];
    sums[tid] = loc;
    __syncthreads();
    for (int off = 1; off < 256; off <<= 1) {
        int t = (tid >= off) ? sums[tid - off] : 0;
        __syncthreads();
        sums[tid] += t;
        __syncthreads();
    }
    int pre = sums[tid] - loc;
    for (int i = s0; i < s1; i++) { int v = ldsc[i]; ldsc[i] = pre; pre += v; }
    __syncthreads();
    if (blockIdx.x == 0) {   // only block 0 publishes rowptr for the gather kernels
        for (int i = tid; i < n; i += 256) rowptr[i] = ldsc[i];
        if (tid == 255) rowptr[n] = pre;
    }
    // fill this block's edges using the LDS prefix
    int e = blockIdx.x * 256 + tid;
    if (e >= E) return;
    int s = src[e], d = dst[e];
    int pos = ldsc[d] + atomicAdd(&fillc[d], 1);
    int cs = cnt_s[s], cd = cnt_s[d];
    float ds = (cs > 0) ? rsqrtf((float)cs) : 0.0f;
    float dd = (cd > 0) ? rsqrtf((float)cd) : 0.0f;
    float nr = rsqrtf((float)cnt_d[s] + 1.0f) * rsqrtf((float)cnt_d[d] + 1.0f);
    ecb[pos] = make_int2(s, __float_as_int(-(ds * dd)));
    egc[pos] = make_int2(s, __float_as_int(nr));
}

// ---------- Cheb gather over tcat slices, 16x edge-unrolled ----------
__global__ __launch_bounds__(256) void gather_cheb_bf(
        const unsigned short* __restrict__ tb, const int* __restrict__ rowptr,
        const int2* __restrict__ edges,
        const unsigned short* __restrict__ base, float alpha, float beta,
        unsigned short* __restrict__ outc, int n) {
    int w = (blockIdx.x * blockDim.x + threadIdx.x) >> 6;
    int lane = threadIdx.x & 63;
    if (w >= n) return;
    float a0 = 0.0f, a1 = 0.0f;
    int rs = rowptr[w], re = rowptr[w + 1];
    for (int b = rs; b < re; b += 64) {
        int cl = 0; float wl = 0.0f;
        if (b + lane < re) { int2 e = edges[b + lane]; cl = e.x; wl = __int_as_float(e.y); }
        int nk16 = (min(64, re - b) + 15) & ~15;   // pad lanes hold cl=0, wl=0
        for (int j = 0; j < nk16; j += 16) {
            int ss[16]; float ww[16]; unsigned uu[16];
            #pragma unroll
            for (int q = 0; q < 16; q++) { ss[q] = __shfl(cl, j + q); ww[q] = __shfl(wl, j + q); }
            #pragma unroll
            for (int q = 0; q < 16; q++) uu[q] = ((const unsigned*)(tb + (size_t)ss[q] * TC))[lane];
            #pragma unroll
            for (int q = 0; q < 16; q++) { a0 += ww[q] * bf_lo(uu[q]); a1 += ww[q] * bf_hi(uu[q]); }
        }
    }
    if (base) {
        unsigned ub = ((const unsigned*)(base + (size_t)w * TC))[lane];
        a0 = alpha * a0 + beta * bf_lo(ub);
        a1 = alpha * a1 + beta * bf_hi(ub);
    } else {
        a0 *= alpha; a1 *= alpha;
    }
    ushort2 o; o.x = f2bf(a0); o.y = f2bf(a1);
    *(ushort2*)(outc + (size_t)w * TC + lane * 2) = o;
}

// ---------- GCN pre-aggregation, 16x edge-unrolled ----------
template<int FPL>   // C = FPL*64, FPL in {2,4}
__global__ __launch_bounds__(256) void gather_gcn_pre(
        const unsigned short* __restrict__ tb, const int* __restrict__ rowptr,
        const int2* __restrict__ edges,
        const int* __restrict__ cnt_d, unsigned short* __restrict__ z, int n) {
    const int C = FPL * 64;
    int w = (blockIdx.x * blockDim.x + threadIdx.x) >> 6;
    int lane = threadIdx.x & 63;
    if (w >= n) return;
    float acc[FPL];
    #pragma unroll
    for (int q = 0; q < FPL; q++) acc[q] = 0.0f;
    int rs = rowptr[w], re = rowptr[w + 1];
    for (int b = rs; b < re; b += 64) {
        int cl = 0; float wl = 0.0f;
        if (b + lane < re) { int2 e = edges[b + lane]; cl = e.x; wl = __int_as_float(e.y); }
        int nk16 = (min(64, re - b) + 15) & ~15;
        for (int j = 0; j < nk16; j += 16) {
            int ss[16]; float ww[16];
            #pragma unroll
            for (int q = 0; q < 16; q++) { ss[q] = __shfl(cl, j + q); ww[q] = __shfl(wl, j + q); }
            if constexpr (FPL == 2) {
                unsigned uu[16];
                #pragma unroll
                for (int q = 0; q < 16; q++) uu[q] = ((const unsigned*)(tb + (size_t)ss[q] * C))[lane];
                #pragma unroll
                for (int q = 0; q < 16; q++) { acc[0] += ww[q] * bf_lo(uu[q]); acc[1] += ww[q] * bf_hi(uu[q]); }
            } else {
                uint2 uu[16];
                #pragma unroll
                for (int q = 0; q < 16; q++) uu[q] = ((const uint2*)(tb + (size_t)ss[q] * C))[lane];
                #pragma unroll
                for (int q = 0; q < 16; q++) {
                    acc[0] += ww[q] * bf_lo(uu[q].x); acc[1] += ww[q] * bf_hi(uu[q].x);
                    acc[2] += ww[q] * bf_lo(uu[q].y); acc[3] += ww[q] * bf_hi(uu[q].y);
                }
            }
        }
    }
    float sn = 1.0f / (float)(cnt_d[w] + 1);   // dinv^2 self-loop term
    if constexpr (FPL == 2) {
        unsigned u = ((const unsigned*)(tb + (size_t)w * C))[lane];
        acc[0] += sn * bf_lo(u); acc[1] += sn * bf_hi(u);
        ushort2 o; o.x = f2bf(acc[0]); o.y = f2bf(acc[1]);
        *(ushort2*)(z + (size_t)w * C + lane * 2) = o;
    } else {
        uint2 u = ((const uint2*)(tb + (size_t)w * C))[lane];
        acc[0] += sn * bf_lo(u.x); acc[1] += sn * bf_hi(u.x);
        acc[2] += sn * bf_lo(u.y); acc[3] += sn * bf_hi(u.y);
        ushort4 o; o.x = f2bf(acc[0]); o.y = f2bf(acc[1]);
        o.z = f2bf(acc[2]); o.w = f2bf(acc[3]);
        *(ushort4*)(z + (size_t)w * C + lane * 4) = o;
    }
}

// ---------- bf16 MFMA GEMM, compile-time K ----------
template<int JT, int KC>
__global__ __launch_bounds__(256) void gemm_bf16(
        const unsigned short* __restrict__ A, const unsigned short* __restrict__ Bt,
        const float* __restrict__ bias,
        unsigned short* __restrict__ Cb, const float* __restrict__ wg,
        float* __restrict__ logits, int M, int N) {
    int m0 = blockIdx.y * 64, n0 = blockIdx.x * (JT * 32);
    int wave = threadIdx.x >> 6, lane = threadIdx.x & 63;
    int wm = (wave & 1) * 32, wn = (wave >> 1) * (JT * 16);
    int l15 = lane & 15, quad = lane >> 4;

    v4f acc[2][JT];
    #pragma unroll
    for (int i = 0; i < 2; i++)
        #pragma unroll
        for (int j = 0; j < JT; j++) acc[i][j] = (v4f){0.f, 0.f, 0.f, 0.f};

    const unsigned short* Ab[2]; bool av[2];
    #pragma unroll
    for (int i = 0; i < 2; i++) {
        int row = m0 + wm + i * 16 + l15;
        av[i] = row < M;
        Ab[i] = A + (size_t)(av[i] ? row : 0) * KC + quad * 8;
    }
    const unsigned short* Bb[JT];
    #pragma unroll
    for (int j = 0; j < JT; j++) {
        int coln = n0 + wn + j * 16 + l15;
        Bb[j] = Bt + (size_t)coln * KC + quad * 8;
    }
    const v8s zero8 = {0, 0, 0, 0, 0, 0, 0, 0};

    #pragma unroll
    for (int k0 = 0; k0 < KC; k0 += 32) {
        v8s a[2], b[JT];
        #pragma unroll
        for (int i = 0; i < 2; i++) a[i] = av[i] ? *(const v8s*)(Ab[i] + k0) : zero8;
        #pragma unroll
        for (int j = 0; j < JT; j++) b[j] = *(const v8s*)(Bb[j] + k0);
        #pragma unroll
        for (int i = 0; i < 2; i++)
            #pragma unroll
            for (int j = 0; j < JT; j++)
                acc[i][j] = __builtin_amdgcn_mfma_f32_16x16x32_bf16(a[i], b[j], acc[i][j], 0, 0, 0);
    }

    float bv[JT], wgj[JT];
    #pragma unroll
    for (int j = 0; j < JT; j++) {
        int coln = n0 + wn + j * 16 + l15;
        bv[j] = bias[coln];
        wgj[j] = wg ? wg[coln] : 0.0f;
    }
    #pragma unroll
    for (int i = 0; i < 2; i++) {
        #pragma unroll
        for (int r = 0; r < 4; r++) {
            int row = m0 + wm + i * 16 + quad * 4 + r;
            if (row >= M) continue;
            float gval = 0.0f;
            #pragma unroll
            for (int j = 0; j < JT; j++) {
                int coln = n0 + wn + j * 16 + l15;
                float v = fmaxf(acc[i][j][r] + bv[j], 0.0f);
                Cb[(size_t)row * N + coln] = f2bf(v);
                gval += v * wgj[j];
            }
            if (wg) {
                #pragma unroll
                for (int off = 1; off < 16; off <<= 1) gval += __shfl_xor(gval, off);
                if (l15 == 0) atomicAdd(&logits[row], gval);
            }
        }
    }
}

// ---------- pool (G x 8 slices, parallel) + FC done-counter fusion ----------
__global__ __launch_bounds__(256) void pool_fc_fused(const unsigned short* __restrict__ h3b,
        const float* __restrict__ logits, const int* __restrict__ gptr,
        float* __restrict__ pooled, int* __restrict__ gdone,
        const float* __restrict__ Wfc, const float* __restrict__ bfc,
        float* __restrict__ out) {
    __shared__ float red[256];
    __shared__ float plds[C3_DIM];
    __shared__ int lastf;
    int g = blockIdx.x, sl = blockIdx.y, tid = threadIdx.x;
    int gs = gptr[g], ge = gptr[g + 1];
    // per-graph softmax stats (redundant per slice-block, logits L2-hot)
    float m = -INFINITY;
    for (int i = gs + tid; i < ge; i += 256) m = fmaxf(m, logits[i]);
    red[tid] = m; __syncthreads();
    for (int off = 128; off > 0; off >>= 1) {
        if (tid < off) red[tid] = fmaxf(red[tid], red[tid + off]);
        __syncthreads();
    }
    m = red[0]; __syncthreads();
    float s = 0.0f;
    for (int i = gs + tid; i < ge; i += 256) s += expf(logits[i] - m);
    red[tid] = s; __syncthreads();
    for (int off = 128; off > 0; off >>= 1) {
        if (tid < off) red[tid] += red[tid + off];
        __syncthreads();
    }
    s = red[0];
    float sinv = (s > 0.0f) ? 1.0f / s : 0.0f;
    // weighted feature partial sum for this slice
    int cnt = ge - gs;
    int i0 = gs + (cnt * sl) / 8;
    int i1 = gs + (cnt * (sl + 1)) / 8;
    float a0 = 0.0f, a1 = 0.0f;
    for (int i = i0; i < i1; i++) {
        float al = expf(logits[i] - m) * sinv;
        unsigned u = ((const unsigned*)(h3b + (size_t)i * C3_DIM))[tid];
        a0 += al * bf_lo(u);
        a1 += al * bf_hi(u);
    }
    if (i1 > i0) {
        atomicAdd(&pooled[(size_t)g * C3_DIM + tid * 2 + 0], a0);
        atomicAdd(&pooled[(size_t)g * C3_DIM + tid * 2 + 1], a1);
    }
    // done-counter: last slice-block for this graph computes FC + log_softmax
    __threadfence();
    __syncthreads();
    if (tid == 0) lastf = (atomicAdd(&gdone[g], 1) == 7) ? 1 : 0;
    __syncthreads();
    if (!lastf) return;
    // coherent read of pooled via device-scope atomic loads
    plds[tid * 2 + 0] = atomicAdd(&pooled[(size_t)g * C3_DIM + tid * 2 + 0], 0.0f);
    plds[tid * 2 + 1] = atomicAdd(&pooled[(size_t)g * C3_DIM + tid * 2 + 1], 0.0f);
    __syncthreads();
    if (tid < 16) {
        float acc = -INFINITY;
        if (tid < NCLS) {
            acc = bfc[tid];
            for (int k = 0; k < C3_DIM; k++)
                acc += plds[k] * Wfc[k * NCLS + tid];
        }
        float mm = acc;
        #pragma unroll
        for (int off = 8; off > 0; off >>= 1) mm = fmaxf(mm, __shfl_xor(mm, off, 16));
        float e = (tid < NCLS) ? expf(acc - mm) : 0.0f;
        float ss = e;
        #pragma unroll
        for (int off = 8; off > 0; off >>= 1) ss += __shfl_xor(ss, off, 16);
        if (tid < NCLS) out[g * NCLS + tid] = acc - mm - logf(ss);
    }
}

// ---------- host ----------
extern "C" void kernel_launch(void* const* d_in, const int* in_sizes, int n_in,
                              void* d_out, int out_size, void* d_ws, size_t ws_size,
                              hipStream_t stream) {
    const float* x      = (const float*)d_in[0];
    const int*   ei     = (const int*)d_in[1];
    const int*   batch  = (const int*)d_in[2];
    const float* W_cheb = (const float*)d_in[3];
    const float* b_cheb = (const float*)d_in[4];
    const float* W_g1   = (const float*)d_in[5];
    const float* b_g1   = (const float*)d_in[6];
    const float* W_g2   = (const float*)d_in[7];
    const float* b_g2   = (const float*)d_in[8];
    const float* w_gate = (const float*)d_in[9];
    const float* W_fc   = (const float*)d_in[11];
    const float* b_fc   = (const float*)d_in[12];
    const int* src = ei;
    const int* dst = ei + N_EDGES;
    float* out = (float*)d_out;

    const int N = N_NODES, E = N_EDGES, G = N_GRAPHS;

    char* Wp = (char*)d_ws;
    auto alloc = [&](size_t bytes) {
        void* p = Wp;
        Wp += (bytes + 255) & ~(size_t)255;
        return p;
    };
    int*   cnt3    = (int*)alloc((size_t)3 * N * 4);   // cnt_s | cnt_d | fillc
    int*   cnt_s   = cnt3;
    int*   cnt_d   = cnt3 + N;
    int*   fillc   = cnt3 + 2 * N;
    int*   rowptr  = (int*)alloc((N + 1) * 4);
    int2*  ecb     = (int2*)alloc((size_t)E * 8);
    int2*  egc     = (int2*)alloc((size_t)E * 8);
    unsigned short* tcat  = (unsigned short*)alloc((size_t)N * TC * 2);
    unsigned short* h1b   = (unsigned short*)alloc((size_t)N * C1_DIM * 2);
    unsigned short* z1b   = (unsigned short*)alloc((size_t)N * C1_DIM * 2);
    unsigned short* h2b   = (unsigned short*)alloc((size_t)N * C2_DIM * 2);
    unsigned short* z2b   = (unsigned short*)alloc((size_t)N * C2_DIM * 2);
    unsigned short* h3b   = (unsigned short*)alloc((size_t)N * C3_DIM * 2);
    unsigned short* Wcb_t = (unsigned short*)alloc((size_t)TC * C1_DIM * 2);
    unsigned short* Wg1_t = (unsigned short*)alloc((size_t)C1_DIM * C2_DIM * 2);
    unsigned short* Wg2_t = (unsigned short*)alloc((size_t)C2_DIM * C3_DIM * 2);
    float* logits  = (float*)alloc(N * 4);
    int*   gptr    = (int*)alloc((G + 1) * 4);
    float* pooled  = (float*)alloc((size_t)G * C3_DIM * 4);
    int*   gdone   = (int*)alloc(G * 4);

    dim3 blk(256);
    auto cdiv = [](int a, int b) { return (a + b - 1) / b; };

    // --- memset counters, fused prep ---
    hipMemsetAsync(cnt3, 0, (size_t)3 * N * sizeof(int), stream);
    hipLaunchKernelGGL(prep_kernel, dim3(cdiv(PREP_TOTAL, 256)), blk, 0, stream,
                       x, tcat, W_cheb, Wcb_t, W_g1, Wg1_t, W_g2, Wg2_t,
                       batch, gptr, logits, pooled, gdone, src, dst, cnt_s, cnt_d);

    // --- CSR fill with embedded redundant scan (scan stage eliminated) ---
    hipLaunchKernelGGL(fill_scan_kernel, dim3(cdiv(E, 256)), blk, 0, stream,
                       src, dst, cnt_s, cnt_d, rowptr, fillc, ecb, egc, E, N);

    const int NWB = cdiv(N, 4);   // gathers: 4 waves/block, 1 node/wave

    // --- Cheb recurrence on tcat slices ---
    hipLaunchKernelGGL(gather_cheb_bf, dim3(NWB), blk, 0, stream,
                       tcat + 0 * F_IN, rowptr, ecb,
                       (const unsigned short*)nullptr, 1.0f, 0.0f, tcat + 1 * F_IN, N);
    hipLaunchKernelGGL(gather_cheb_bf, dim3(NWB), blk, 0, stream,
                       tcat + 1 * F_IN, rowptr, ecb,
                       tcat + 0 * F_IN, 2.0f, -1.0f, tcat + 2 * F_IN, N);
    hipLaunchKernelGGL(gather_cheb_bf, dim3(NWB), blk, 0, stream,
                       tcat + 2 * F_IN, rowptr, ecb,
                       tcat + 1 * F_IN, 2.0f, -1.0f, tcat + 3 * F_IN, N);
    hipLaunchKernelGGL(gather_cheb_bf, dim3(NWB), blk, 0, stream,
                       tcat + 3 * F_IN, rowptr, ecb,
                       tcat + 2 * F_IN, 2.0f, -1.0f, tcat + 4 * F_IN, N);

    // --- GEMM1: h1 = relu(Tcat @ Wcb^T + b)  K=640 ---
    hipLaunchKernelGGL((gemm_bf16<2, TC>), dim3(C1_DIM / 64, cdiv(N, 64)), blk, 0, stream,
                       tcat, Wcb_t, b_cheb, h1b,
                       (const float*)nullptr, (float*)nullptr, N, C1_DIM);

    // --- GCN1 aggregate + GEMM2 (K=128) ---
    hipLaunchKernelGGL(gather_gcn_pre<2>, dim3(NWB), blk, 0, stream,
                       h1b, rowptr, egc, cnt_d, z1b, N);
    hipLaunchKernelGGL((gemm_bf16<4, C1_DIM>), dim3(C2_DIM / 128, cdiv(N, 64)), blk, 0, stream,
                       z1b, Wg1_t, b_g1, h2b,
                       (const float*)nullptr, (float*)nullptr, N, C2_DIM);

    // --- GCN2 aggregate + GEMM3 (K=256) + fused gate dot ---
    hipLaunchKernelGGL(gather_gcn_pre<4>, dim3(NWB), blk, 0, stream,
                       h2b, rowptr, egc, cnt_d, z2b, N);
    hipLaunchKernelGGL((gemm_bf16<4, C2_DIM>), dim3(C3_DIM / 128, cdiv(N, 64)), blk, 0, stream,
                       z2b, Wg2_t, b_g2, h3b,
                       w_gate, logits, N, C3_DIM);

    // --- fused pool (G x 8, parallel) + FC via done-counter (fc stage eliminated) ---
    hipLaunchKernelGGL(pool_fc_fused, dim3(G, 8), blk, 0, stream,
                       h3b, logits, gptr, pooled, gdone, W_fc, b_fc, out);
}

// Round 13
// 263.186 us; speedup vs baseline: 1.2914x; 1.1053x over previous
//
#include <hip/hip_runtime.h>
#include <hip/hip_bf16.h>
#include <math.h>

#define N_NODES 10000
#define N_EDGES 160000
#define N_GRAPHS 64
#define F_IN    128
#define C1_DIM  128
#define C2_DIM  256
#define C3_DIM  512
#define K_CHEB  5
#define NCLS    10
#define TC      (K_CHEB * F_IN)    // 640

typedef short v8s __attribute__((ext_vector_type(8)));
typedef float v4f __attribute__((ext_vector_type(4)));

// ---------- bf16 helpers ----------
static __device__ __forceinline__ unsigned short f2bf(float f) {
    unsigned u = __float_as_uint(f);
    unsigned r = (u + 0x7FFFu + ((u >> 16) & 1u)) >> 16;   // RNE
    return (unsigned short)r;
}
static __device__ __forceinline__ float bf_lo(unsigned u) { return __uint_as_float(u << 16); }
static __device__ __forceinline__ float bf_hi(unsigned u) { return __uint_as_float(u & 0xFFFF0000u); }

// ---------- fused prep ----------
#define PREP_A (N_NODES * 32)            // x conv, 4 floats per item
#define PREP_B (TC * C1_DIM)             // W_cheb transpose (write-coalesced)
#define PREP_C (C1_DIM * C2_DIM)         // W_g1
#define PREP_D (C2_DIM * C3_DIM)         // W_g2
#define PREP_E N_NODES                   // gptr
#define PREP_F N_NODES                   // zero logits
#define PREP_H (N_GRAPHS * C3_DIM)       // zero pooled
#define PREP_G N_EDGES                   // degree count (guarded tail)
#define PREP_TOTAL (PREP_A + PREP_B + PREP_C + PREP_D + PREP_E + PREP_F + PREP_H + PREP_G)
__global__ void prep_kernel(const float* __restrict__ x, unsigned short* __restrict__ tcat,
                            const float* __restrict__ Wcheb, unsigned short* __restrict__ Wcb_t,
                            const float* __restrict__ Wg1, unsigned short* __restrict__ Wg1_t,
                            const float* __restrict__ Wg2, unsigned short* __restrict__ Wg2_t,
                            const int* __restrict__ batch, int* __restrict__ gptr,
                            float* __restrict__ logits, float* __restrict__ pooled,
                            const int* __restrict__ src, const int* __restrict__ dst,
                            int* __restrict__ cnt_s, int* __restrict__ cnt_d) {
    int id = blockIdx.x * blockDim.x + threadIdx.x;
    if (id < PREP_A) {
        int n = id >> 5, f = (id & 31) * 4;
        float4 v = *(const float4*)(x + (size_t)n * F_IN + f);
        ushort4 o; o.x = f2bf(v.x); o.y = f2bf(v.y); o.z = f2bf(v.z); o.w = f2bf(v.w);
        *(ushort4*)(tcat + (size_t)n * TC + f) = o;
        return;
    }
    id -= PREP_A;
    if (id < PREP_B) {
        int k = id % TC, n = id / TC;
        Wcb_t[(size_t)n * TC + k] = f2bf(Wcheb[(size_t)k * C1_DIM + n]);
        return;
    }
    id -= PREP_B;
    if (id < PREP_C) {
        int k = id % C1_DIM, n = id / C1_DIM;
        Wg1_t[(size_t)n * C1_DIM + k] = f2bf(Wg1[(size_t)k * C2_DIM + n]);
        return;
    }
    id -= PREP_C;
    if (id < PREP_D) {
        int k = id % C2_DIM, n = id / C2_DIM;
        Wg2_t[(size_t)n * C2_DIM + k] = f2bf(Wg2[(size_t)k * C3_DIM + n]);
        return;
    }
    id -= PREP_D;
    if (id < PREP_E) {
        int i = id;
        int b = batch[i];
        if (i == 0) { for (int g = 0; g <= b; g++) gptr[g] = 0; }
        else {
            int bp = batch[i - 1];
            for (int g = bp + 1; g <= b; g++) gptr[g] = i;
        }
        if (i == N_NODES - 1) { for (int g = b + 1; g <= N_GRAPHS; g++) gptr[g] = N_NODES; }
        return;
    }
    id -= PREP_E;
    if (id < PREP_F) { logits[id] = 0.0f; return; }
    id -= PREP_F;
    if (id < PREP_H) { pooled[id] = 0.0f; return; }
    id -= PREP_H;
    if (id < PREP_G) {   // guarded tail (R6 lesson)
        atomicAdd(&cnt_s[src[id]], 1);
        atomicAdd(&cnt_d[dst[id]], 1);
    }
}

// ---------- CSR fill with EMBEDDED per-block redundant scan (no scan stage) ----------
__global__ __launch_bounds__(256) void fill_scan_kernel(
        const int* __restrict__ src, const int* __restrict__ dst,
        const int* __restrict__ cnt_s, const int* __restrict__ cnt_d,
        int* __restrict__ rowptr, int* __restrict__ fillc,
        int2* __restrict__ ecb, int2* __restrict__ egc, int E, int n) {
    __shared__ int ldsc[N_NODES];
    __shared__ int sums[256];
    int tid = threadIdx.x;
    for (int i = tid; i < n; i += 256) ldsc[i] = cnt_d[i];
    __syncthreads();
    int chunk = (n + 255) / 256;
    int s0 = min(n, tid * chunk), s1 = min(n, s0 + chunk);
    int loc = 0;
    for (int i = s0; i < s1; i++) loc += ldsc[i];
    sums[tid] = loc;
    __syncthreads();
    for (int off = 1; off < 256; off <<= 1) {
        int t = (tid >= off) ? sums[tid - off] : 0;
        __syncthreads();
        sums[tid] += t;
        __syncthreads();
    }
    int pre = sums[tid] - loc;
    for (int i = s0; i < s1; i++) { int v = ldsc[i]; ldsc[i] = pre; pre += v; }
    __syncthreads();
    if (blockIdx.x == 0) {   // block 0 publishes rowptr for the gather kernels
        for (int i = tid; i < n; i += 256) rowptr[i] = ldsc[i];
        if (tid == 255) rowptr[n] = pre;
    }
    int e = blockIdx.x * 256 + tid;
    if (e >= E) return;
    int s = src[e], d = dst[e];
    int pos = ldsc[d] + atomicAdd(&fillc[d], 1);
    int cs = cnt_s[s], cd = cnt_s[d];
    float ds = (cs > 0) ? rsqrtf((float)cs) : 0.0f;
    float dd = (cd > 0) ? rsqrtf((float)cd) : 0.0f;
    float nr = rsqrtf((float)cnt_d[s] + 1.0f) * rsqrtf((float)cnt_d[d] + 1.0f);
    ecb[pos] = make_int2(s, __float_as_int(-(ds * dd)));
    egc[pos] = make_int2(s, __float_as_int(nr));
}

// ---------- Cheb gather over tcat slices, 16x edge-unrolled ----------
__global__ __launch_bounds__(256) void gather_cheb_bf(
        const unsigned short* __restrict__ tb, const int* __restrict__ rowptr,
        const int2* __restrict__ edges,
        const unsigned short* __restrict__ base, float alpha, float beta,
        unsigned short* __restrict__ outc, int n) {
    int w = (blockIdx.x * blockDim.x + threadIdx.x) >> 6;
    int lane = threadIdx.x & 63;
    if (w >= n) return;
    float a0 = 0.0f, a1 = 0.0f;
    int rs = rowptr[w], re = rowptr[w + 1];
    for (int b = rs; b < re; b += 64) {
        int cl = 0; float wl = 0.0f;
        if (b + lane < re) { int2 e = edges[b + lane]; cl = e.x; wl = __int_as_float(e.y); }
        int nk16 = (min(64, re - b) + 15) & ~15;   // pad lanes hold cl=0, wl=0
        for (int j = 0; j < nk16; j += 16) {
            int ss[16]; float ww[16]; unsigned uu[16];
            #pragma unroll
            for (int q = 0; q < 16; q++) { ss[q] = __shfl(cl, j + q); ww[q] = __shfl(wl, j + q); }
            #pragma unroll
            for (int q = 0; q < 16; q++) uu[q] = ((const unsigned*)(tb + (size_t)ss[q] * TC))[lane];
            #pragma unroll
            for (int q = 0; q < 16; q++) { a0 += ww[q] * bf_lo(uu[q]); a1 += ww[q] * bf_hi(uu[q]); }
        }
    }
    if (base) {
        unsigned ub = ((const unsigned*)(base + (size_t)w * TC))[lane];
        a0 = alpha * a0 + beta * bf_lo(ub);
        a1 = alpha * a1 + beta * bf_hi(ub);
    } else {
        a0 *= alpha; a1 *= alpha;
    }
    ushort2 o; o.x = f2bf(a0); o.y = f2bf(a1);
    *(ushort2*)(outc + (size_t)w * TC + lane * 2) = o;
}

// ---------- GCN pre-aggregation, 16x edge-unrolled ----------
template<int FPL>   // C = FPL*64, FPL in {2,4}
__global__ __launch_bounds__(256) void gather_gcn_pre(
        const unsigned short* __restrict__ tb, const int* __restrict__ rowptr,
        const int2* __restrict__ edges,
        const int* __restrict__ cnt_d, unsigned short* __restrict__ z, int n) {
    const int C = FPL * 64;
    int w = (blockIdx.x * blockDim.x + threadIdx.x) >> 6;
    int lane = threadIdx.x & 63;
    if (w >= n) return;
    float acc[FPL];
    #pragma unroll
    for (int q = 0; q < FPL; q++) acc[q] = 0.0f;
    int rs = rowptr[w], re = rowptr[w + 1];
    for (int b = rs; b < re; b += 64) {
        int cl = 0; float wl = 0.0f;
        if (b + lane < re) { int2 e = edges[b + lane]; cl = e.x; wl = __int_as_float(e.y); }
        int nk16 = (min(64, re - b) + 15) & ~15;
        for (int j = 0; j < nk16; j += 16) {
            int ss[16]; float ww[16];
            #pragma unroll
            for (int q = 0; q < 16; q++) { ss[q] = __shfl(cl, j + q); ww[q] = __shfl(wl, j + q); }
            if constexpr (FPL == 2) {
                unsigned uu[16];
                #pragma unroll
                for (int q = 0; q < 16; q++) uu[q] = ((const unsigned*)(tb + (size_t)ss[q] * C))[lane];
                #pragma unroll
                for (int q = 0; q < 16; q++) { acc[0] += ww[q] * bf_lo(uu[q]); acc[1] += ww[q] * bf_hi(uu[q]); }
            } else {
                uint2 uu[16];
                #pragma unroll
                for (int q = 0; q < 16; q++) uu[q] = ((const uint2*)(tb + (size_t)ss[q] * C))[lane];
                #pragma unroll
                for (int q = 0; q < 16; q++) {
                    acc[0] += ww[q] * bf_lo(uu[q].x); acc[1] += ww[q] * bf_hi(uu[q].x);
                    acc[2] += ww[q] * bf_lo(uu[q].y); acc[3] += ww[q] * bf_hi(uu[q].y);
                }
            }
        }
    }
    float sn = 1.0f / (float)(cnt_d[w] + 1);   // dinv^2 self-loop term
    if constexpr (FPL == 2) {
        unsigned u = ((const unsigned*)(tb + (size_t)w * C))[lane];
        acc[0] += sn * bf_lo(u); acc[1] += sn * bf_hi(u);
        ushort2 o; o.x = f2bf(acc[0]); o.y = f2bf(acc[1]);
        *(ushort2*)(z + (size_t)w * C + lane * 2) = o;
    } else {
        uint2 u = ((const uint2*)(tb + (size_t)w * C))[lane];
        acc[0] += sn * bf_lo(u.x); acc[1] += sn * bf_hi(u.x);
        acc[2] += sn * bf_lo(u.y); acc[3] += sn * bf_hi(u.y);
        ushort4 o; o.x = f2bf(acc[0]); o.y = f2bf(acc[1]);
        o.z = f2bf(acc[2]); o.w = f2bf(acc[3]);
        *(ushort4*)(z + (size_t)w * C + lane * 4) = o;
    }
}

// ---------- bf16 MFMA GEMM, compile-time K ----------
template<int JT, int KC>
__global__ __launch_bounds__(256) void gemm_bf16(
        const unsigned short* __restrict__ A, const unsigned short* __restrict__ Bt,
        const float* __restrict__ bias,
        unsigned short* __restrict__ Cb, const float* __restrict__ wg,
        float* __restrict__ logits, int M, int N) {
    int m0 = blockIdx.y * 64, n0 = blockIdx.x * (JT * 32);
    int wave = threadIdx.x >> 6, lane = threadIdx.x & 63;
    int wm = (wave & 1) * 32, wn = (wave >> 1) * (JT * 16);
    int l15 = lane & 15, quad = lane >> 4;

    v4f acc[2][JT];
    #pragma unroll
    for (int i = 0; i < 2; i++)
        #pragma unroll
        for (int j = 0; j < JT; j++) acc[i][j] = (v4f){0.f, 0.f, 0.f, 0.f};

    const unsigned short* Ab[2]; bool av[2];
    #pragma unroll
    for (int i = 0; i < 2; i++) {
        int row = m0 + wm + i * 16 + l15;
        av[i] = row < M;
        Ab[i] = A + (size_t)(av[i] ? row : 0) * KC + quad * 8;
    }
    const unsigned short* Bb[JT];
    #pragma unroll
    for (int j = 0; j < JT; j++) {
        int coln = n0 + wn + j * 16 + l15;
        Bb[j] = Bt + (size_t)coln * KC + quad * 8;
    }
    const v8s zero8 = {0, 0, 0, 0, 0, 0, 0, 0};

    #pragma unroll
    for (int k0 = 0; k0 < KC; k0 += 32) {
        v8s a[2], b[JT];
        #pragma unroll
        for (int i = 0; i < 2; i++) a[i] = av[i] ? *(const v8s*)(Ab[i] + k0) : zero8;
        #pragma unroll
        for (int j = 0; j < JT; j++) b[j] = *(const v8s*)(Bb[j] + k0);
        #pragma unroll
        for (int i = 0; i < 2; i++)
            #pragma unroll
            for (int j = 0; j < JT; j++)
                acc[i][j] = __builtin_amdgcn_mfma_f32_16x16x32_bf16(a[i], b[j], acc[i][j], 0, 0, 0);
    }

    float bv[JT], wgj[JT];
    #pragma unroll
    for (int j = 0; j < JT; j++) {
        int coln = n0 + wn + j * 16 + l15;
        bv[j] = bias[coln];
        wgj[j] = wg ? wg[coln] : 0.0f;
    }
    #pragma unroll
    for (int i = 0; i < 2; i++) {
        #pragma unroll
        for (int r = 0; r < 4; r++) {
            int row = m0 + wm + i * 16 + quad * 4 + r;
            if (row >= M) continue;
            float gval = 0.0f;
            #pragma unroll
            for (int j = 0; j < JT; j++) {
                int coln = n0 + wn + j * 16 + l15;
                float v = fmaxf(acc[i][j][r] + bv[j], 0.0f);
                Cb[(size_t)row * N + coln] = f2bf(v);
                gval += v * wgj[j];
            }
            if (wg) {
                #pragma unroll
                for (int off = 1; off < 16; off <<= 1) gval += __shfl_xor(gval, off);
                if (l15 == 0) atomicAdd(&logits[row], gval);
            }
        }
    }
}

// ---------- pool: grid (G, 8 slices), stats inline, plain atomics, NO fence ----------
__global__ __launch_bounds__(256) void pool_partial(const unsigned short* __restrict__ h3b,
        const float* __restrict__ logits, const int* __restrict__ gptr,
        float* __restrict__ pooled) {
    __shared__ float red[256];
    int g = blockIdx.x, sl = blockIdx.y, tid = threadIdx.x;
    int gs = gptr[g], ge = gptr[g + 1];
    float m = -INFINITY;
    for (int i = gs + tid; i < ge; i += 256) m = fmaxf(m, logits[i]);
    red[tid] = m; __syncthreads();
    for (int off = 128; off > 0; off >>= 1) {
        if (tid < off) red[tid] = fmaxf(red[tid], red[tid + off]);
        __syncthreads();
    }
    m = red[0]; __syncthreads();
    float s = 0.0f;
    for (int i = gs + tid; i < ge; i += 256) s += expf(logits[i] - m);
    red[tid] = s; __syncthreads();
    for (int off = 128; off > 0; off >>= 1) {
        if (tid < off) red[tid] += red[tid + off];
        __syncthreads();
    }
    s = red[0];
    float sinv = (s > 0.0f) ? 1.0f / s : 0.0f;
    int cnt = ge - gs;
    int i0 = gs + (cnt * sl) / 8;
    int i1 = gs + (cnt * (sl + 1)) / 8;
    float a0 = 0.0f, a1 = 0.0f;
    for (int i = i0; i < i1; i++) {
        float al = expf(logits[i] - m) * sinv;
        unsigned u = ((const unsigned*)(h3b + (size_t)i * C3_DIM))[tid];
        a0 += al * bf_lo(u);
        a1 += al * bf_hi(u);
    }
    if (i1 > i0) {
        atomicAdd(&pooled[(size_t)g * C3_DIM + tid * 2 + 0], a0);
        atomicAdd(&pooled[(size_t)g * C3_DIM + tid * 2 + 1], a1);
    }
}

// ---------- FC + log_softmax ----------
__global__ void fc_kernel(const float* __restrict__ pooled, const float* __restrict__ Wfc,
                          const float* __restrict__ bfc, float* __restrict__ out) {
    int g = blockIdx.x;
    int t = threadIdx.x;
    float acc = -INFINITY;
    if (t < NCLS) {
        acc = bfc[t];
        for (int k = 0; k < C3_DIM; k++)
            acc += pooled[(size_t)g * C3_DIM + k] * Wfc[k * NCLS + t];
    }
    float m = acc;
    #pragma unroll
    for (int off = 8; off > 0; off >>= 1) m = fmaxf(m, __shfl_xor(m, off, 16));
    float e = (t < NCLS) ? expf(acc - m) : 0.0f;
    float s = e;
    #pragma unroll
    for (int off = 8; off > 0; off >>= 1) s += __shfl_xor(s, off, 16);
    if (t < NCLS) out[g * NCLS + t] = acc - m - logf(s);
}

// ---------- host ----------
extern "C" void kernel_launch(void* const* d_in, const int* in_sizes, int n_in,
                              void* d_out, int out_size, void* d_ws, size_t ws_size,
                              hipStream_t stream) {
    const float* x      = (const float*)d_in[0];
    const int*   ei     = (const int*)d_in[1];
    const int*   batch  = (const int*)d_in[2];
    const float* W_cheb = (const float*)d_in[3];
    const float* b_cheb = (const float*)d_in[4];
    const float* W_g1   = (const float*)d_in[5];
    const float* b_g1   = (const float*)d_in[6];
    const float* W_g2   = (const float*)d_in[7];
    const float* b_g2   = (const float*)d_in[8];
    const float* w_gate = (const float*)d_in[9];
    const float* W_fc   = (const float*)d_in[11];
    const float* b_fc   = (const float*)d_in[12];
    const int* src = ei;
    const int* dst = ei + N_EDGES;
    float* out = (float*)d_out;

    const int N = N_NODES, E = N_EDGES, G = N_GRAPHS;

    char* Wp = (char*)d_ws;
    auto alloc = [&](size_t bytes) {
        void* p = Wp;
        Wp += (bytes + 255) & ~(size_t)255;
        return p;
    };
    int*   cnt3    = (int*)alloc((size_t)3 * N * 4);   // cnt_s | cnt_d | fillc
    int*   cnt_s   = cnt3;
    int*   cnt_d   = cnt3 + N;
    int*   fillc   = cnt3 + 2 * N;
    int*   rowptr  = (int*)alloc((N + 1) * 4);
    int2*  ecb     = (int2*)alloc((size_t)E * 8);
    int2*  egc     = (int2*)alloc((size_t)E * 8);
    unsigned short* tcat  = (unsigned short*)alloc((size_t)N * TC * 2);
    unsigned short* h1b   = (unsigned short*)alloc((size_t)N * C1_DIM * 2);
    unsigned short* z1b   = (unsigned short*)alloc((size_t)N * C1_DIM * 2);
    unsigned short* h2b   = (unsigned short*)alloc((size_t)N * C2_DIM * 2);
    unsigned short* z2b   = (unsigned short*)alloc((size_t)N * C2_DIM * 2);
    unsigned short* h3b   = (unsigned short*)alloc((size_t)N * C3_DIM * 2);
    unsigned short* Wcb_t = (unsigned short*)alloc((size_t)TC * C1_DIM * 2);
    unsigned short* Wg1_t = (unsigned short*)alloc((size_t)C1_DIM * C2_DIM * 2);
    unsigned short* Wg2_t = (unsigned short*)alloc((size_t)C2_DIM * C3_DIM * 2);
    float* logits  = (float*)alloc(N * 4);
    int*   gptr    = (int*)alloc((G + 1) * 4);
    float* pooled  = (float*)alloc((size_t)G * C3_DIM * 4);

    dim3 blk(256);
    auto cdiv = [](int a, int b) { return (a + b - 1) / b; };

    // --- memset counters, fused prep ---
    hipMemsetAsync(cnt3, 0, (size_t)3 * N * sizeof(int), stream);
    hipLaunchKernelGGL(prep_kernel, dim3(cdiv(PREP_TOTAL, 256)), blk, 0, stream,
                       x, tcat, W_cheb, Wcb_t, W_g1, Wg1_t, W_g2, Wg2_t,
                       batch, gptr, logits, pooled, src, dst, cnt_s, cnt_d);

    // --- CSR fill with embedded redundant scan (scan stage eliminated) ---
    hipLaunchKernelGGL(fill_scan_kernel, dim3(cdiv(E, 256)), blk, 0, stream,
                       src, dst, cnt_s, cnt_d, rowptr, fillc, ecb, egc, E, N);

    const int NWB = cdiv(N, 4);   // gathers: 4 waves/block, 1 node/wave

    // --- Cheb recurrence on tcat slices ---
    hipLaunchKernelGGL(gather_cheb_bf, dim3(NWB), blk, 0, stream,
                       tcat + 0 * F_IN, rowptr, ecb,
                       (const unsigned short*)nullptr, 1.0f, 0.0f, tcat + 1 * F_IN, N);
    hipLaunchKernelGGL(gather_cheb_bf, dim3(NWB), blk, 0, stream,
                       tcat + 1 * F_IN, rowptr, ecb,
                       tcat + 0 * F_IN, 2.0f, -1.0f, tcat + 2 * F_IN, N);
    hipLaunchKernelGGL(gather_cheb_bf, dim3(NWB), blk, 0, stream,
                       tcat + 2 * F_IN, rowptr, ecb,
                       tcat + 1 * F_IN, 2.0f, -1.0f, tcat + 3 * F_IN, N);
    hipLaunchKernelGGL(gather_cheb_bf, dim3(NWB), blk, 0, stream,
                       tcat + 3 * F_IN, rowptr, ecb,
                       tcat + 2 * F_IN, 2.0f, -1.0f, tcat + 4 * F_IN, N);

    // --- GEMM1: h1 = relu(Tcat @ Wcb^T + b)  K=640 ---
    hipLaunchKernelGGL((gemm_bf16<2, TC>), dim3(C1_DIM / 64, cdiv(N, 64)), blk, 0, stream,
                       tcat, Wcb_t, b_cheb, h1b,
                       (const float*)nullptr, (float*)nullptr, N, C1_DIM);

    // --- GCN1 aggregate + GEMM2 (K=128) ---
    hipLaunchKernelGGL(gather_gcn_pre<2>, dim3(NWB), blk, 0, stream,
                       h1b, rowptr, egc, cnt_d, z1b, N);
    hipLaunchKernelGGL((gemm_bf16<4, C1_DIM>), dim3(C2_DIM / 128, cdiv(N, 64)), blk, 0, stream,
                       z1b, Wg1_t, b_g1, h2b,
                       (const float*)nullptr, (float*)nullptr, N, C2_DIM);

    // --- GCN2 aggregate + GEMM3 (K=256) + fused gate dot ---
    hipLaunchKernelGGL(gather_gcn_pre<4>, dim3(NWB), blk, 0, stream,
                       h2b, rowptr, egc, cnt_d, z2b, N);
    hipLaunchKernelGGL((gemm_bf16<4, C2_DIM>), dim3(C3_DIM / 128, cdiv(N, 64)), blk, 0, stream,
                       z2b, Wg2_t, b_g2, h3b,
                       w_gate, logits, N, C3_DIM);

    // --- pool (G x 8, parallel, no fence) + FC ---
    hipLaunchKernelGGL(pool_partial, dim3(G, 8), blk, 0, stream, h3b, logits, gptr, pooled);
    hipLaunchKernelGGL(fc_kernel, dim3(G), dim3(64), 0, stream, pooled, W_fc, b_fc, out);
}